// Round 3
// baseline (5266.343 us; speedup 1.0000x reference)
//
#include <hip/hip_runtime.h>

// gamma[i] = || (e0 + G e0 + G^2 e0 + G^3 e0 + G^4 e0)/5 [drugs[i]] ||^2
// R3: replace full counting-sort CSR (263us scatter, 8x write-amp) with
// 64-row bucket binning (blockwise-aggregated scatter -> sequential write
// fronts) + bucket-SpMM with 64x64 f32 LDS accumulator (ds_add_f32).

#define RB 64          // rows per bucket
#define RB_SHIFT 6
#define KPT 32         // edges per thread in binning scatter
#define BIN_CHUNK (256 * KPT)
#define MAXNB 2048     // supports N <= 131072

// histogram of edges per bucket (direct global atomics: 1563 addrs, ~2K/addr,
// parallel chains across L2 banks -> few us)
__global__ __launch_bounds__(256) void bhist_kernel(const int* __restrict__ row,
                                                    int* __restrict__ cnt, int E) {
    int stride = gridDim.x * blockDim.x;
    for (int e = blockIdx.x * blockDim.x + threadIdx.x; e < E; e += stride)
        atomicAdd(&cnt[row[e] >> RB_SHIFT], 1);
}

// single-block exclusive scan over nb (<= 2048) bucket counts.
// writes boff[0..nb] and a cursor copy.
__global__ __launch_bounds__(256) void bscan_kernel(const int* __restrict__ cnt,
                                                    int* __restrict__ boff,
                                                    int* __restrict__ gcur, int nb) {
    __shared__ int sdata[256];
    int t = threadIdx.x;
    int v[8];
    int sum = 0;
#pragma unroll
    for (int j = 0; j < 8; ++j) {
        int idx = t * 8 + j;
        v[j] = (idx < nb) ? cnt[idx] : 0;
        sum += v[j];
    }
    sdata[t] = sum;
    __syncthreads();
    for (int d = 1; d < 256; d <<= 1) {
        int tmp = (t >= d) ? sdata[t - d] : 0;
        __syncthreads();
        sdata[t] += tmp;
        __syncthreads();
    }
    int base = sdata[t] - sum;  // exclusive
#pragma unroll
    for (int j = 0; j < 8; ++j) {
        int idx = t * 8 + j;
        if (idx < nb) { boff[idx] = base; gcur[idx] = base; }
        base += v[j];
    }
    if (t == 255) boff[nb] = sdata[255];
}

// blockwise-aggregated binning scatter: per 8192-edge chunk, LDS histogram,
// one global cursor atomic per (chunk,bucket), then grouped writes
// (~10 consecutive int2 per bucket front per chunk -> L2 merges lines).
// payload: packed = (row_in_bucket << 20) | col  (col < 2^20), val as bits.
__global__ __launch_bounds__(256) void bin_scatter_kernel(const int* __restrict__ row,
                                                          const int* __restrict__ col,
                                                          const float* __restrict__ val,
                                                          int* __restrict__ gcur,
                                                          int2* __restrict__ edges,
                                                          int E, int nb) {
    __shared__ int lcnt[MAXNB];
    __shared__ int lbase[MAXNB];
    int t = threadIdx.x;
    int chunk0 = blockIdx.x * BIN_CHUNK;
    for (int i = t; i < nb; i += 256) lcnt[i] = 0;
    __syncthreads();

    int packed[KPT];
    float fv[KPT];
    int loffb[KPT];  // (bucket << 16) | local_offset
#pragma unroll
    for (int j = 0; j < KPT; ++j) {
        int e = chunk0 + j * 256 + t;  // coalesced per j
        if (e < E) {
            int r = row[e];
            int b = r >> RB_SHIFT;
            packed[j] = ((r & (RB - 1)) << 20) | col[e];
            fv[j] = val[e];
            int lo = atomicAdd(&lcnt[b], 1);
            loffb[j] = (b << 16) | lo;
        } else {
            packed[j] = -1;
            loffb[j] = 0;
            fv[j] = 0.f;
        }
    }
    __syncthreads();
    for (int b = t; b < nb; b += 256) {
        int c = lcnt[b];
        lbase[b] = c ? atomicAdd(&gcur[b], c) : 0;
    }
    __syncthreads();
#pragma unroll
    for (int j = 0; j < KPT; ++j) {
        if (packed[j] >= 0) {
            int b = loffb[j] >> 16;
            int lo = loffb[j] & 0xFFFF;
            edges[lbase[b] + lo] = make_int2(packed[j], __float_as_int(fv[j]));
        }
    }
}

// bucket SpMM: one block per 64-row bucket, 64x64 f32 LDS accumulator.
// waves stream the bucket's (unsorted) edges; lane = dim; LDS f32 atomics.
__global__ __launch_bounds__(256) void bspmm_kernel(const float* __restrict__ x,
                                                    float* __restrict__ y,
                                                    const int* __restrict__ boff,
                                                    const int2* __restrict__ edges, int N) {
    __shared__ float acc[RB * 64];  // 16 KB
    int b = blockIdx.x;
    int t = threadIdx.x;
    for (int i = t; i < RB * 64; i += 256) acc[i] = 0.f;
    __syncthreads();

    int s = boff[b], e = boff[b + 1];
    int lane = t & 63, wid = t >> 6;
    int i = s + wid;
    // 4 waves stride by 4; unroll 4 (i, i+4, i+8, i+12) for MLP
    for (; i + 12 < e; i += 16) {
        int2 m0 = edges[i], m1 = edges[i + 4], m2 = edges[i + 8], m3 = edges[i + 12];
        float x0 = x[(size_t)(m0.x & 0xFFFFF) * 64 + lane];
        float x1 = x[(size_t)(m1.x & 0xFFFFF) * 64 + lane];
        float x2 = x[(size_t)(m2.x & 0xFFFFF) * 64 + lane];
        float x3 = x[(size_t)(m3.x & 0xFFFFF) * 64 + lane];
        atomicAdd(&acc[(m0.x >> 20) * 64 + lane], __int_as_float(m0.y) * x0);
        atomicAdd(&acc[(m1.x >> 20) * 64 + lane], __int_as_float(m1.y) * x1);
        atomicAdd(&acc[(m2.x >> 20) * 64 + lane], __int_as_float(m2.y) * x2);
        atomicAdd(&acc[(m3.x >> 20) * 64 + lane], __int_as_float(m3.y) * x3);
    }
    for (; i < e; i += 4) {
        int2 m = edges[i];
        float xv = x[(size_t)(m.x & 0xFFFFF) * 64 + lane];
        atomicAdd(&acc[(m.x >> 20) * 64 + lane], __int_as_float(m.y) * xv);
    }
    __syncthreads();

    int base_row = b << RB_SHIFT;
    int rows = min(RB, N - base_row);
    for (int idx = t; idx < rows * 64; idx += 256)
        y[(size_t)base_row * 64 + idx] = acc[idx];
}

__global__ __launch_bounds__(256) void gather_init_kernel(float* __restrict__ sacc,
                                                          const float* __restrict__ src,
                                                          const int* __restrict__ drugs, int B) {
    int idx = blockIdx.x * 256 + threadIdx.x;
    if (idx >= B * 64) return;
    int i = idx >> 6, d = idx & 63;
    sacc[idx] = src[(size_t)drugs[i] * 64 + d];
}

__global__ __launch_bounds__(256) void gather_add_kernel(float* __restrict__ sacc,
                                                         const float* __restrict__ src,
                                                         const int* __restrict__ drugs, int B) {
    int idx = blockIdx.x * 256 + threadIdx.x;
    if (idx >= B * 64) return;
    int i = idx >> 6, d = idx & 63;
    sacc[idx] += src[(size_t)drugs[i] * 64 + d];
}

// gamma[i] = || sacc[i] * 0.2 ||^2  (wave per drug row)
__global__ __launch_bounds__(256) void gamma_kernel(const float* __restrict__ sacc,
                                                    float* __restrict__ out, int B) {
    int w = (blockIdx.x * 256 + threadIdx.x) >> 6;
    int lane = threadIdx.x & 63;
    if (w >= B) return;
    float v = sacc[(size_t)w * 64 + lane] * 0.2f;
    v = v * v;
    for (int o = 32; o > 0; o >>= 1) v += __shfl_down(v, o, 64);
    if (lane == 0) out[w] = v;
}

extern "C" void kernel_launch(void* const* d_in, const int* in_sizes, int n_in,
                              void* d_out, int out_size, void* d_ws, size_t ws_size,
                              hipStream_t stream) {
    (void)n_in; (void)ws_size; (void)out_size;
    const float* emb       = (const float*)d_in[0];
    const float* edge_vals = (const float*)d_in[1];
    const int*   edge_row  = (const int*)d_in[2];
    const int*   edge_col  = (const int*)d_in[3];
    const int*   drugs     = (const int*)d_in[4];
    int N = in_sizes[0] / 64;
    int E = in_sizes[1];
    int B = in_sizes[4];
    float* gamma_out = (float*)d_out;

    int nb = (N + RB - 1) >> RB_SHIFT;  // 1563 for N=100000

    char* ws = (char*)d_ws;
    size_t o = 0;
    auto alloc = [&](size_t bytes) -> void* {
        o = (o + 255) & ~(size_t)255;
        void* p = ws + o;
        o += bytes;
        return p;
    };
    int*   cnt  = (int*)alloc((size_t)nb * 4);
    int*   boff = (int*)alloc((size_t)(nb + 1) * 4);
    int*   gcur = (int*)alloc((size_t)nb * 4);
    int2*  edges = (int2*)alloc((size_t)E * 8);
    float* bufA = (float*)alloc((size_t)N * 64 * 4);
    float* bufB = (float*)alloc((size_t)N * 64 * 4);
    float* sacc = (float*)alloc((size_t)B * 64 * 4);

    // ---- bucket binning ----
    hipMemsetAsync(cnt, 0, (size_t)nb * 4, stream);
    bhist_kernel<<<2048, 256, 0, stream>>>(edge_row, cnt, E);
    bscan_kernel<<<1, 256, 0, stream>>>(cnt, boff, gcur, nb);
    int nchunks = (E + BIN_CHUNK - 1) / BIN_CHUNK;
    bin_scatter_kernel<<<nchunks, 256, 0, stream>>>(edge_row, edge_col, edge_vals,
                                                    gcur, edges, E, nb);

    // ---- 5-term sum over drug rows ----
    int gatherGrid = (B * 64 + 255) / 256;
    gather_init_kernel<<<gatherGrid, 256, 0, stream>>>(sacc, emb, drugs, B);

    bspmm_kernel<<<nb, 256, 0, stream>>>(emb, bufA, boff, edges, N);   // G e0
    gather_add_kernel<<<gatherGrid, 256, 0, stream>>>(sacc, bufA, drugs, B);
    bspmm_kernel<<<nb, 256, 0, stream>>>(bufA, bufB, boff, edges, N);  // G^2 e0
    gather_add_kernel<<<gatherGrid, 256, 0, stream>>>(sacc, bufB, drugs, B);
    bspmm_kernel<<<nb, 256, 0, stream>>>(bufB, bufA, boff, edges, N);  // G^3 e0
    gather_add_kernel<<<gatherGrid, 256, 0, stream>>>(sacc, bufA, drugs, B);
    bspmm_kernel<<<nb, 256, 0, stream>>>(bufA, bufB, boff, edges, N);  // G^4 e0
    gather_add_kernel<<<gatherGrid, 256, 0, stream>>>(sacc, bufB, drugs, B);

    gamma_kernel<<<(B + 3) / 4, 256, 0, stream>>>(sacc, gamma_out, B);
}

// Round 4
// 1036.818 us; speedup vs baseline: 5.0793x; 5.0793x over previous
//
#include <hip/hip_runtime.h>

// gamma[i] = || (e0 + G e0 + G^2 e0 + G^3 e0 + G^4 e0)/5 [drugs[i]] ||^2
// R4: two-phase CSR build (bucket radix-partition with block-aggregated runs,
// then per-bucket in-LDS counting sort) -> no 8x write-amp, no fp atomics.
// SpMM = R2's proven pull kernel (wave per row, lane = dim).

#define RB 64
#define RB_SHIFT 6
#define NBMAX 2048          // max buckets (N <= 131072)
#define CHUNK 8192          // edges per partition block

__global__ __launch_bounds__(256) void bhist_kernel(const int* __restrict__ row,
                                                    int* __restrict__ cnt, int E) {
    int stride = gridDim.x * blockDim.x;
    for (int e = blockIdx.x * blockDim.x + threadIdx.x; e < E; e += stride)
        atomicAdd(&cnt[row[e] >> RB_SHIFT], 1);
}

// single-block exclusive scan over nb (<= 2048) bucket counts -> boff, gcur
__global__ __launch_bounds__(256) void bscan_kernel(const int* __restrict__ cnt,
                                                    int* __restrict__ boff,
                                                    int* __restrict__ gcur, int nb) {
    __shared__ int sdata[256];
    int t = threadIdx.x;
    int v[8];
    int sum = 0;
#pragma unroll
    for (int j = 0; j < 8; ++j) {
        int idx = t * 8 + j;
        v[j] = (idx < nb) ? cnt[idx] : 0;
        sum += v[j];
    }
    sdata[t] = sum;
    __syncthreads();
    for (int d = 1; d < 256; d <<= 1) {
        int tmp = (t >= d) ? sdata[t - d] : 0;
        __syncthreads();
        sdata[t] += tmp;
        __syncthreads();
    }
    int base = sdata[t] - sum;  // exclusive
#pragma unroll
    for (int j = 0; j < 8; ++j) {
        int idx = t * 8 + j;
        if (idx < nb) { boff[idx] = base; gcur[idx] = base; }
        base += v[j];
    }
    if (t == 255) boff[nb] = sdata[255];
}

// phase 1: partition edges into row-buckets. Per 8192-edge chunk: LDS count,
// reserve global range (1 atomic per bucket per chunk), re-read + scatter.
// Runs are block-contiguous -> same-XCD L2 merges lines (write-amp ~1.2x).
// payload: (row_in_bucket << 20) | col, val bits.
__global__ __launch_bounds__(512) void part_kernel(const int* __restrict__ row,
                                                   const int* __restrict__ col,
                                                   const float* __restrict__ val,
                                                   int* __restrict__ gcur,
                                                   int2* __restrict__ edges,
                                                   int E, int nb) {
    __shared__ int lcnt[NBMAX];
    __shared__ int lbase[NBMAX];
    int t = threadIdx.x;
    int s = blockIdx.x * CHUNK;
    int e = min(s + CHUNK, E);
    for (int i = t; i < nb; i += 512) lcnt[i] = 0;
    __syncthreads();
    for (int i = s + t; i < e; i += 512)
        atomicAdd(&lcnt[row[i] >> RB_SHIFT], 1);
    __syncthreads();
    for (int b = t; b < nb; b += 512) {
        int c = lcnt[b];
        lbase[b] = c ? atomicAdd(&gcur[b], c) : 0;
        lcnt[b] = 0;
    }
    __syncthreads();
    for (int i = s + t; i < e; i += 512) {
        int r = row[i];
        int b = r >> RB_SHIFT;
        int lo = atomicAdd(&lcnt[b], 1);
        edges[lbase[b] + lo] = make_int2(((r & (RB - 1)) << 20) | col[i],
                                         __float_as_int(val[i]));
    }
}

// phase 2: per-bucket counting sort by row (in-LDS int counters), emit
// row-sorted edges (col,val) + CSR off[]. Reads bucket twice (L2-hot).
__global__ __launch_bounds__(256) void bsort_kernel(const int* __restrict__ boff,
                                                    const int2* __restrict__ ein,
                                                    int2* __restrict__ eout,
                                                    int* __restrict__ off, int N) {
    __shared__ int rcnt[RB];
    __shared__ int rcur[RB];
    int b = blockIdx.x, t = threadIdx.x;
    int s = boff[b], e = boff[b + 1];
    if (t < RB) rcnt[t] = 0;
    __syncthreads();
    for (int i = s + t; i < e; i += 256)
        atomicAdd(&rcnt[ein[i].x >> 20], 1);
    __syncthreads();
    if (t < RB) {
        int v = rcnt[t];
        int x = v;
        for (int d = 1; d < RB; d <<= 1) {
            int y = __shfl_up(x, d, 64);
            if (t >= d) x += y;
        }
        int excl = x - v;
        rcur[t] = excl;
        int idx = (b << RB_SHIFT) + t;
        if (idx <= N) off[idx] = s + excl;
        if (t == RB - 1) {
            int idx2 = (b << RB_SHIFT) + RB;
            if (idx2 <= N) off[idx2] = e;
        }
    }
    __syncthreads();
    for (int i = s + t; i < e; i += 256) {
        int2 m = ein[i];
        int pos = atomicAdd(&rcur[m.x >> 20], 1);
        eout[s + pos] = make_int2(m.x & 0xFFFFF, m.y);
    }
}

// pull SpMM: one wave per row, lane = dim. y[r] = sum val * x[col]
__global__ __launch_bounds__(256) void spmm_kernel(const float* __restrict__ x,
                                                   float* __restrict__ y,
                                                   const int* __restrict__ off,
                                                   const int2* __restrict__ edges, int N) {
    int w = (blockIdx.x * 256 + threadIdx.x) >> 6;
    int lane = threadIdx.x & 63;
    if (w >= N) return;
    int s = off[w], e = off[w + 1];
    float a0 = 0.f, a1 = 0.f, a2 = 0.f, a3 = 0.f;
    int i = s;
    for (; i + 4 <= e; i += 4) {
        int2 m0 = edges[i], m1 = edges[i + 1], m2 = edges[i + 2], m3 = edges[i + 3];
        a0 += __int_as_float(m0.y) * x[(size_t)m0.x * 64 + lane];
        a1 += __int_as_float(m1.y) * x[(size_t)m1.x * 64 + lane];
        a2 += __int_as_float(m2.y) * x[(size_t)m2.x * 64 + lane];
        a3 += __int_as_float(m3.y) * x[(size_t)m3.x * 64 + lane];
    }
    for (; i < e; ++i) {
        int2 m = edges[i];
        a0 += __int_as_float(m.y) * x[(size_t)m.x * 64 + lane];
    }
    y[(size_t)w * 64 + lane] = (a0 + a1) + (a2 + a3);
}

__global__ __launch_bounds__(256) void gather_init_kernel(float* __restrict__ sacc,
                                                          const float* __restrict__ src,
                                                          const int* __restrict__ drugs, int B) {
    int idx = blockIdx.x * 256 + threadIdx.x;
    if (idx >= B * 64) return;
    int i = idx >> 6, d = idx & 63;
    sacc[idx] = src[(size_t)drugs[i] * 64 + d];
}

__global__ __launch_bounds__(256) void gather_add_kernel(float* __restrict__ sacc,
                                                         const float* __restrict__ src,
                                                         const int* __restrict__ drugs, int B) {
    int idx = blockIdx.x * 256 + threadIdx.x;
    if (idx >= B * 64) return;
    int i = idx >> 6, d = idx & 63;
    sacc[idx] += src[(size_t)drugs[i] * 64 + d];
}

// gamma[i] = || sacc[i] * 0.2 ||^2  (wave per drug row)
__global__ __launch_bounds__(256) void gamma_kernel(const float* __restrict__ sacc,
                                                    float* __restrict__ out, int B) {
    int w = (blockIdx.x * 256 + threadIdx.x) >> 6;
    int lane = threadIdx.x & 63;
    if (w >= B) return;
    float v = sacc[(size_t)w * 64 + lane] * 0.2f;
    v = v * v;
    for (int o = 32; o > 0; o >>= 1) v += __shfl_down(v, o, 64);
    if (lane == 0) out[w] = v;
}

extern "C" void kernel_launch(void* const* d_in, const int* in_sizes, int n_in,
                              void* d_out, int out_size, void* d_ws, size_t ws_size,
                              hipStream_t stream) {
    (void)n_in; (void)ws_size; (void)out_size;
    const float* emb       = (const float*)d_in[0];
    const float* edge_vals = (const float*)d_in[1];
    const int*   edge_row  = (const int*)d_in[2];
    const int*   edge_col  = (const int*)d_in[3];
    const int*   drugs     = (const int*)d_in[4];
    int N = in_sizes[0] / 64;
    int E = in_sizes[1];
    int B = in_sizes[4];
    float* gamma_out = (float*)d_out;

    int nb = (N + RB - 1) >> RB_SHIFT;  // 1563 for N=100000

    char* ws = (char*)d_ws;
    size_t o = 0;
    auto alloc = [&](size_t bytes) -> void* {
        o = (o + 255) & ~(size_t)255;
        void* p = ws + o;
        o += bytes;
        return p;
    };
    int*   cnt   = (int*)alloc((size_t)nb * 4);
    int*   boff  = (int*)alloc((size_t)(nb + 1) * 4);
    int*   gcur  = (int*)alloc((size_t)nb * 4);
    int*   off   = (int*)alloc((size_t)(N + 1) * 4);
    // ein region aliases bufA (ein dead before first spmm writes bufA)
    size_t ebytes = (size_t)E * 8;
    size_t abytes = (size_t)N * 64 * 4;
    char*  reg0  = (char*)alloc(ebytes > abytes ? ebytes : abytes);
    int2*  ein   = (int2*)reg0;
    float* bufA  = (float*)reg0;
    int2*  eout  = (int2*)alloc(ebytes);
    float* bufB  = (float*)alloc(abytes);
    float* sacc  = (float*)alloc((size_t)B * 64 * 4);

    // ---- CSR build ----
    hipMemsetAsync(cnt, 0, (size_t)nb * 4, stream);
    bhist_kernel<<<2048, 256, 0, stream>>>(edge_row, cnt, E);
    bscan_kernel<<<1, 256, 0, stream>>>(cnt, boff, gcur, nb);
    int nchunks = (E + CHUNK - 1) / CHUNK;
    part_kernel<<<nchunks, 512, 0, stream>>>(edge_row, edge_col, edge_vals,
                                             gcur, ein, E, nb);
    bsort_kernel<<<nb, 256, 0, stream>>>(boff, ein, eout, off, N);

    // ---- 5-term sum over drug rows ----
    int gatherGrid = (B * 64 + 255) / 256;
    gather_init_kernel<<<gatherGrid, 256, 0, stream>>>(sacc, emb, drugs, B);

    int spmmGrid = (N + 3) / 4;
    spmm_kernel<<<spmmGrid, 256, 0, stream>>>(emb, bufA, off, eout, N);   // G e0
    gather_add_kernel<<<gatherGrid, 256, 0, stream>>>(sacc, bufA, drugs, B);
    spmm_kernel<<<spmmGrid, 256, 0, stream>>>(bufA, bufB, off, eout, N);  // G^2 e0
    gather_add_kernel<<<gatherGrid, 256, 0, stream>>>(sacc, bufB, drugs, B);
    spmm_kernel<<<spmmGrid, 256, 0, stream>>>(bufB, bufA, off, eout, N);  // G^3 e0
    gather_add_kernel<<<gatherGrid, 256, 0, stream>>>(sacc, bufA, drugs, B);
    spmm_kernel<<<spmmGrid, 256, 0, stream>>>(bufA, bufB, off, eout, N);  // G^4 e0
    gather_add_kernel<<<gatherGrid, 256, 0, stream>>>(sacc, bufB, drugs, B);

    gamma_kernel<<<(B + 3) / 4, 256, 0, stream>>>(sacc, gamma_out, B);
}

// Round 5
// 553.248 us; speedup vs baseline: 9.5190x; 1.8741x over previous
//
#include <hip/hip_runtime.h>

// gamma[i] = || (e0 + G e0 + G^2 e0 + G^3 e0 + G^4 e0)/5 [drugs[i]] ||^2
// R5: atomic-free 3-pass radix partition (count matrix -> scan -> scatter
// with LDS cursors) kills R4's 467us contended-atomic histogram. SpMM now
// quarter-wave (4 rows/wave, 16 lanes x float4) for 4x VMEM instr reduction.

#define RB 64
#define RB_SHIFT 6
#define NBMAX 2048          // max buckets (N <= 131072)
#define CHUNK 8192          // edges per partition chunk
#define SCAN_CHUNK 4096

// pass A: per-chunk LDS histogram -> cmat[b * nchunks + c] (no global atomics)
__global__ __launch_bounds__(256) void countA_kernel(const int* __restrict__ row,
                                                     int* __restrict__ cmat,
                                                     int E, int nb, int nchunks) {
    __shared__ int lcnt[NBMAX];
    int t = threadIdx.x, c = blockIdx.x;
    int s = c * CHUNK, e = min(s + CHUNK, E);
    for (int i = t; i < nb; i += 256) lcnt[i] = 0;
    __syncthreads();
    for (int i = s + t; i < e; i += 256)
        atomicAdd(&lcnt[row[i] >> RB_SHIFT], 1);
    __syncthreads();
    for (int b = t; b < nb; b += 256)
        cmat[(size_t)b * nchunks + c] = lcnt[b];
}

// scan pass 1: per-4096-chunk block sums
__global__ __launch_bounds__(256) void scanA_kernel(const int* __restrict__ data,
                                                    int* __restrict__ partial, int M) {
    __shared__ int sdata[256];
    int t = threadIdx.x;
    int base = blockIdx.x * SCAN_CHUNK;
    int sum = 0;
#pragma unroll
    for (int j = 0; j < 16; ++j) {
        int idx = base + j * 256 + t;
        if (idx < M) sum += data[idx];
    }
    sdata[t] = sum;
    __syncthreads();
    for (int d = 128; d > 0; d >>= 1) {
        if (t < d) sdata[t] += sdata[t + d];
        __syncthreads();
    }
    if (t == 0) partial[blockIdx.x] = sdata[0];
}

// scan pass 2: exclusive scan of block sums (nblk <= 256)
__global__ __launch_bounds__(256) void scanB_kernel(int* __restrict__ partial, int nblk) {
    __shared__ int sdata[256];
    int t = threadIdx.x;
    int v = (t < nblk) ? partial[t] : 0;
    sdata[t] = v;
    __syncthreads();
    for (int d = 1; d < 256; d <<= 1) {
        int tmp = (t >= d) ? sdata[t - d] : 0;
        __syncthreads();
        sdata[t] += tmp;
        __syncthreads();
    }
    if (t < nblk) partial[t] = sdata[t] - v;
}

// scan pass 3: apply -> in-place exclusive scan of cmat
__global__ __launch_bounds__(256) void scanC_kernel(int* __restrict__ data,
                                                    const int* __restrict__ partial, int M) {
    __shared__ int sdata[256];
    int t = threadIdx.x;
    int base = blockIdx.x * SCAN_CHUNK;
    int v[16];
    int sum = 0;
#pragma unroll
    for (int j = 0; j < 16; ++j) {
        int idx = base + t * 16 + j;
        v[j] = (idx < M) ? data[idx] : 0;
        sum += v[j];
    }
    sdata[t] = sum;
    __syncthreads();
    for (int d = 1; d < 256; d <<= 1) {
        int tmp = (t >= d) ? sdata[t - d] : 0;
        __syncthreads();
        sdata[t] += tmp;
        __syncthreads();
    }
    int excl = sdata[t] - sum + partial[blockIdx.x];
#pragma unroll
    for (int j = 0; j < 16; ++j) {
        int idx = base + t * 16 + j;
        if (idx < M) data[idx] = excl;
        excl += v[j];
    }
}

__global__ __launch_bounds__(256) void extract_boff_kernel(const int* __restrict__ cmat,
                                                           int* __restrict__ boff,
                                                           int nb, int nchunks, int E) {
    int b = blockIdx.x * 256 + threadIdx.x;
    if (b < nb) boff[b] = cmat[(size_t)b * nchunks];
    if (b == nb) boff[nb] = E;
}

// scatter: LDS cursors seeded from scanned cmat -> zero global atomics.
// payload: (row_in_bucket << 20) | col, val bits.
__global__ __launch_bounds__(256) void part2_kernel(const int* __restrict__ row,
                                                    const int* __restrict__ col,
                                                    const float* __restrict__ val,
                                                    const int* __restrict__ cmat,
                                                    int2* __restrict__ edges,
                                                    int E, int nb, int nchunks) {
    __shared__ int lcur[NBMAX];
    int t = threadIdx.x, c = blockIdx.x;
    int s = c * CHUNK, e = min(s + CHUNK, E);
    for (int b = t; b < nb; b += 256)
        lcur[b] = cmat[(size_t)b * nchunks + c];
    __syncthreads();
    for (int i = s + t; i < e; i += 256) {
        int r = row[i];
        int b = r >> RB_SHIFT;
        int lo = atomicAdd(&lcur[b], 1);
        edges[lo] = make_int2(((r & (RB - 1)) << 20) | col[i],
                              __float_as_int(val[i]));
    }
}

// per-bucket counting sort by row (LDS int counters) -> row-sorted (col,val) + CSR off[]
__global__ __launch_bounds__(256) void bsort_kernel(const int* __restrict__ boff,
                                                    const int2* __restrict__ ein,
                                                    int2* __restrict__ eout,
                                                    int* __restrict__ off, int N) {
    __shared__ int rcnt[RB];
    __shared__ int rcur[RB];
    int b = blockIdx.x, t = threadIdx.x;
    int s = boff[b], e = boff[b + 1];
    if (t < RB) rcnt[t] = 0;
    __syncthreads();
    for (int i = s + t; i < e; i += 256)
        atomicAdd(&rcnt[ein[i].x >> 20], 1);
    __syncthreads();
    if (t < RB) {
        int v = rcnt[t];
        int x = v;
        for (int d = 1; d < RB; d <<= 1) {
            int y = __shfl_up(x, d, 64);
            if (t >= d) x += y;
        }
        int excl = x - v;
        rcur[t] = excl;
        int idx = (b << RB_SHIFT) + t;
        if (idx <= N) off[idx] = s + excl;
        if (t == RB - 1) {
            int idx2 = (b << RB_SHIFT) + RB;
            if (idx2 <= N) off[idx2] = e;
        }
    }
    __syncthreads();
    for (int i = s + t; i < e; i += 256) {
        int2 m = ein[i];
        int pos = atomicAdd(&rcur[m.x >> 20], 1);
        eout[s + pos] = make_int2(m.x & 0xFFFFF, m.y);
    }
}

// pull SpMM, quarter-wave: 4 rows/wave, 16 lanes x float4 per row.
__global__ __launch_bounds__(256) void spmm_kernel(const float* __restrict__ x,
                                                   float* __restrict__ y,
                                                   const int* __restrict__ off,
                                                   const int2* __restrict__ edges, int N) {
    int wv = (blockIdx.x * 256 + threadIdx.x) >> 6;
    int lane = threadIdx.x & 63;
    int q = lane >> 4, l4 = lane & 15;
    int r = wv * 4 + q;
    bool valid = r < N;
    int s = 0, e = 0;
    if (valid) { s = off[r]; e = off[r + 1]; }
    float4 A0 = make_float4(0.f, 0.f, 0.f, 0.f);
    float4 A1 = A0, A2 = A0, A3 = A0;
    int i = s;
    for (; i + 4 <= e; i += 4) {
        int2 m0 = edges[i], m1 = edges[i + 1], m2 = edges[i + 2], m3 = edges[i + 3];
        float4 x0 = *(const float4*)(x + (size_t)m0.x * 64 + l4 * 4);
        float4 x1 = *(const float4*)(x + (size_t)m1.x * 64 + l4 * 4);
        float4 x2 = *(const float4*)(x + (size_t)m2.x * 64 + l4 * 4);
        float4 x3 = *(const float4*)(x + (size_t)m3.x * 64 + l4 * 4);
        float v0 = __int_as_float(m0.y), v1 = __int_as_float(m1.y);
        float v2 = __int_as_float(m2.y), v3 = __int_as_float(m3.y);
        A0.x += v0 * x0.x; A0.y += v0 * x0.y; A0.z += v0 * x0.z; A0.w += v0 * x0.w;
        A1.x += v1 * x1.x; A1.y += v1 * x1.y; A1.z += v1 * x1.z; A1.w += v1 * x1.w;
        A2.x += v2 * x2.x; A2.y += v2 * x2.y; A2.z += v2 * x2.z; A2.w += v2 * x2.w;
        A3.x += v3 * x3.x; A3.y += v3 * x3.y; A3.z += v3 * x3.z; A3.w += v3 * x3.w;
    }
    for (; i < e; ++i) {
        int2 m = edges[i];
        float4 xv = *(const float4*)(x + (size_t)m.x * 64 + l4 * 4);
        float v = __int_as_float(m.y);
        A0.x += v * xv.x; A0.y += v * xv.y; A0.z += v * xv.z; A0.w += v * xv.w;
    }
    if (valid) {
        float4 R;
        R.x = (A0.x + A1.x) + (A2.x + A3.x);
        R.y = (A0.y + A1.y) + (A2.y + A3.y);
        R.z = (A0.z + A1.z) + (A2.z + A3.z);
        R.w = (A0.w + A1.w) + (A2.w + A3.w);
        *(float4*)(y + (size_t)r * 64 + l4 * 4) = R;
    }
}

__global__ __launch_bounds__(256) void gather_init_kernel(float* __restrict__ sacc,
                                                          const float* __restrict__ src,
                                                          const int* __restrict__ drugs, int B) {
    int idx = blockIdx.x * 256 + threadIdx.x;
    if (idx >= B * 64) return;
    int i = idx >> 6, d = idx & 63;
    sacc[idx] = src[(size_t)drugs[i] * 64 + d];
}

__global__ __launch_bounds__(256) void gather_add_kernel(float* __restrict__ sacc,
                                                         const float* __restrict__ src,
                                                         const int* __restrict__ drugs, int B) {
    int idx = blockIdx.x * 256 + threadIdx.x;
    if (idx >= B * 64) return;
    int i = idx >> 6, d = idx & 63;
    sacc[idx] += src[(size_t)drugs[i] * 64 + d];
}

// gamma[i] = || sacc[i] * 0.2 ||^2  (wave per drug row)
__global__ __launch_bounds__(256) void gamma_kernel(const float* __restrict__ sacc,
                                                    float* __restrict__ out, int B) {
    int w = (blockIdx.x * 256 + threadIdx.x) >> 6;
    int lane = threadIdx.x & 63;
    if (w >= B) return;
    float v = sacc[(size_t)w * 64 + lane] * 0.2f;
    v = v * v;
    for (int o = 32; o > 0; o >>= 1) v += __shfl_down(v, o, 64);
    if (lane == 0) out[w] = v;
}

extern "C" void kernel_launch(void* const* d_in, const int* in_sizes, int n_in,
                              void* d_out, int out_size, void* d_ws, size_t ws_size,
                              hipStream_t stream) {
    (void)n_in; (void)ws_size; (void)out_size;
    const float* emb       = (const float*)d_in[0];
    const float* edge_vals = (const float*)d_in[1];
    const int*   edge_row  = (const int*)d_in[2];
    const int*   edge_col  = (const int*)d_in[3];
    const int*   drugs     = (const int*)d_in[4];
    int N = in_sizes[0] / 64;
    int E = in_sizes[1];
    int B = in_sizes[4];
    float* gamma_out = (float*)d_out;

    int nb = (N + RB - 1) >> RB_SHIFT;          // 1563
    int nchunks = (E + CHUNK - 1) / CHUNK;      // 391
    int M = nb * nchunks;                       // 611K

    char* ws = (char*)d_ws;
    size_t o = 0;
    auto alloc = [&](size_t bytes) -> void* {
        o = (o + 255) & ~(size_t)255;
        void* p = ws + o;
        o += bytes;
        return p;
    };
    int*   cmat  = (int*)alloc((size_t)M * 4);
    int*   partial = (int*)alloc(1024);
    int*   boff  = (int*)alloc((size_t)(nb + 1) * 4);
    int*   off   = (int*)alloc((size_t)(N + 1) * 4);
    size_t ebytes = (size_t)E * 8;
    size_t abytes = (size_t)N * 64 * 4;
    char*  reg0  = (char*)alloc(ebytes > abytes ? ebytes : abytes);
    int2*  ein   = (int2*)reg0;                 // aliases bufA (ein dead before spmm)
    float* bufA  = (float*)reg0;
    int2*  eout  = (int2*)alloc(ebytes);
    float* bufB  = (float*)alloc(abytes);
    float* sacc  = (float*)alloc((size_t)B * 64 * 4);

    // ---- atomic-free CSR build ----
    countA_kernel<<<nchunks, 256, 0, stream>>>(edge_row, cmat, E, nb, nchunks);
    int nscan = (M + SCAN_CHUNK - 1) / SCAN_CHUNK;  // 150 <= 256
    scanA_kernel<<<nscan, 256, 0, stream>>>(cmat, partial, M);
    scanB_kernel<<<1, 256, 0, stream>>>(partial, nscan);
    scanC_kernel<<<nscan, 256, 0, stream>>>(cmat, partial, M);
    extract_boff_kernel<<<(nb + 256) / 256, 256, 0, stream>>>(cmat, boff, nb, nchunks, E);
    part2_kernel<<<nchunks, 256, 0, stream>>>(edge_row, edge_col, edge_vals,
                                              cmat, ein, E, nb, nchunks);
    bsort_kernel<<<nb, 256, 0, stream>>>(boff, ein, eout, off, N);

    // ---- 5-term sum over drug rows ----
    int gatherGrid = (B * 64 + 255) / 256;
    gather_init_kernel<<<gatherGrid, 256, 0, stream>>>(sacc, emb, drugs, B);

    int spmmGrid = (N + 15) / 16;
    spmm_kernel<<<spmmGrid, 256, 0, stream>>>(emb, bufA, off, eout, N);   // G e0
    gather_add_kernel<<<gatherGrid, 256, 0, stream>>>(sacc, bufA, drugs, B);
    spmm_kernel<<<spmmGrid, 256, 0, stream>>>(bufA, bufB, off, eout, N);  // G^2 e0
    gather_add_kernel<<<gatherGrid, 256, 0, stream>>>(sacc, bufB, drugs, B);
    spmm_kernel<<<spmmGrid, 256, 0, stream>>>(bufB, bufA, off, eout, N);  // G^3 e0
    gather_add_kernel<<<gatherGrid, 256, 0, stream>>>(sacc, bufA, drugs, B);
    spmm_kernel<<<spmmGrid, 256, 0, stream>>>(bufA, bufB, off, eout, N);  // G^4 e0
    gather_add_kernel<<<gatherGrid, 256, 0, stream>>>(sacc, bufB, drugs, B);

    gamma_kernel<<<(B + 3) / 4, 256, 0, stream>>>(sacc, gamma_out, B);
}

// Round 6
// 350.220 us; speedup vs baseline: 15.0372x; 1.5797x over previous
//
#include <hip/hip_runtime.h>

// gamma[i] = || (e0 + G e0 + G^2 e0 + G^3 e0 + G^4 e0)/5 [drugs[i]] ||^2
// R6: d-chain state in bf16 (halves L2-miss gather traffic, the R5 bound);
// eighth-wave SpMM (8 lanes x 8 dims/lane, 8 rows/wave, unroll 4).
// e0's direct contribution stays f32-exact (gather_init reads emb).

typedef unsigned int u32;

#define RB 64
#define RB_SHIFT 6
#define NBMAX 2048          // max buckets (N <= 131072)
#define CHUNK 8192          // edges per partition chunk
#define SCAN_CHUNK 4096

// ---------------- CSR build (unchanged from R5) ----------------

__global__ __launch_bounds__(256) void countA_kernel(const int* __restrict__ row,
                                                     int* __restrict__ cmat,
                                                     int E, int nb, int nchunks) {
    __shared__ int lcnt[NBMAX];
    int t = threadIdx.x, c = blockIdx.x;
    int s = c * CHUNK, e = min(s + CHUNK, E);
    for (int i = t; i < nb; i += 256) lcnt[i] = 0;
    __syncthreads();
    for (int i = s + t; i < e; i += 256)
        atomicAdd(&lcnt[row[i] >> RB_SHIFT], 1);
    __syncthreads();
    for (int b = t; b < nb; b += 256)
        cmat[(size_t)b * nchunks + c] = lcnt[b];
}

__global__ __launch_bounds__(256) void scanA_kernel(const int* __restrict__ data,
                                                    int* __restrict__ partial, int M) {
    __shared__ int sdata[256];
    int t = threadIdx.x;
    int base = blockIdx.x * SCAN_CHUNK;
    int sum = 0;
#pragma unroll
    for (int j = 0; j < 16; ++j) {
        int idx = base + j * 256 + t;
        if (idx < M) sum += data[idx];
    }
    sdata[t] = sum;
    __syncthreads();
    for (int d = 128; d > 0; d >>= 1) {
        if (t < d) sdata[t] += sdata[t + d];
        __syncthreads();
    }
    if (t == 0) partial[blockIdx.x] = sdata[0];
}

__global__ __launch_bounds__(256) void scanB_kernel(int* __restrict__ partial, int nblk) {
    __shared__ int sdata[256];
    int t = threadIdx.x;
    int v = (t < nblk) ? partial[t] : 0;
    sdata[t] = v;
    __syncthreads();
    for (int d = 1; d < 256; d <<= 1) {
        int tmp = (t >= d) ? sdata[t - d] : 0;
        __syncthreads();
        sdata[t] += tmp;
        __syncthreads();
    }
    if (t < nblk) partial[t] = sdata[t] - v;
}

__global__ __launch_bounds__(256) void scanC_kernel(int* __restrict__ data,
                                                    const int* __restrict__ partial, int M) {
    __shared__ int sdata[256];
    int t = threadIdx.x;
    int base = blockIdx.x * SCAN_CHUNK;
    int v[16];
    int sum = 0;
#pragma unroll
    for (int j = 0; j < 16; ++j) {
        int idx = base + t * 16 + j;
        v[j] = (idx < M) ? data[idx] : 0;
        sum += v[j];
    }
    sdata[t] = sum;
    __syncthreads();
    for (int d = 1; d < 256; d <<= 1) {
        int tmp = (t >= d) ? sdata[t - d] : 0;
        __syncthreads();
        sdata[t] += tmp;
        __syncthreads();
    }
    int excl = sdata[t] - sum + partial[blockIdx.x];
#pragma unroll
    for (int j = 0; j < 16; ++j) {
        int idx = base + t * 16 + j;
        if (idx < M) data[idx] = excl;
        excl += v[j];
    }
}

__global__ __launch_bounds__(256) void extract_boff_kernel(const int* __restrict__ cmat,
                                                           int* __restrict__ boff,
                                                           int nb, int nchunks, int E) {
    int b = blockIdx.x * 256 + threadIdx.x;
    if (b < nb) boff[b] = cmat[(size_t)b * nchunks];
    if (b == nb) boff[nb] = E;
}

__global__ __launch_bounds__(256) void part2_kernel(const int* __restrict__ row,
                                                    const int* __restrict__ col,
                                                    const float* __restrict__ val,
                                                    const int* __restrict__ cmat,
                                                    int2* __restrict__ edges,
                                                    int E, int nb, int nchunks) {
    __shared__ int lcur[NBMAX];
    int t = threadIdx.x, c = blockIdx.x;
    int s = c * CHUNK, e = min(s + CHUNK, E);
    for (int b = t; b < nb; b += 256)
        lcur[b] = cmat[(size_t)b * nchunks + c];
    __syncthreads();
    for (int i = s + t; i < e; i += 256) {
        int r = row[i];
        int b = r >> RB_SHIFT;
        int lo = atomicAdd(&lcur[b], 1);
        edges[lo] = make_int2(((r & (RB - 1)) << 20) | col[i],
                              __float_as_int(val[i]));
    }
}

__global__ __launch_bounds__(256) void bsort_kernel(const int* __restrict__ boff,
                                                    const int2* __restrict__ ein,
                                                    int2* __restrict__ eout,
                                                    int* __restrict__ off, int N) {
    __shared__ int rcnt[RB];
    __shared__ int rcur[RB];
    int b = blockIdx.x, t = threadIdx.x;
    int s = boff[b], e = boff[b + 1];
    if (t < RB) rcnt[t] = 0;
    __syncthreads();
    for (int i = s + t; i < e; i += 256)
        atomicAdd(&rcnt[ein[i].x >> 20], 1);
    __syncthreads();
    if (t < RB) {
        int v = rcnt[t];
        int x = v;
        for (int d = 1; d < RB; d <<= 1) {
            int y = __shfl_up(x, d, 64);
            if (t >= d) x += y;
        }
        int excl = x - v;
        rcur[t] = excl;
        int idx = (b << RB_SHIFT) + t;
        if (idx <= N) off[idx] = s + excl;
        if (t == RB - 1) {
            int idx2 = (b << RB_SHIFT) + RB;
            if (idx2 <= N) off[idx2] = e;
        }
    }
    __syncthreads();
    for (int i = s + t; i < e; i += 256) {
        int2 m = ein[i];
        int pos = atomicAdd(&rcur[m.x >> 20], 1);
        eout[s + pos] = make_int2(m.x & 0xFFFFF, m.y);
    }
}

// ---------------- bf16 helpers ----------------

static __device__ inline u32 pk_bf16(float lo, float hi) {
    u32 a = __float_as_uint(lo), b = __float_as_uint(hi);
    a += 0x7fffu + ((a >> 16) & 1u);   // RNE
    b += 0x7fffu + ((b >> 16) & 1u);
    return (a >> 16) | (b & 0xffff0000u);
}

// emb (f32, N x 64) -> embh (bf16x2 packed dwords, N x 32)
__global__ __launch_bounds__(256) void cvt_kernel(const float* __restrict__ src,
                                                  u32* __restrict__ dst, int n32) {
    int idx = blockIdx.x * 256 + threadIdx.x;
    if (idx >= n32) return;
    float2 f = *(const float2*)(src + (size_t)idx * 2);
    dst[idx] = pk_bf16(f.x, f.y);
}

// ---------------- SpMM: bf16 in, bf16 out ----------------
// 8 lanes per row, 8 dims per lane (dwordx4 = 8 bf16), 8 rows per wave,
// 4 edges in flight per row.
__global__ __launch_bounds__(256) void spmmh_kernel(const u32* __restrict__ xh,
                                                    u32* __restrict__ yh,
                                                    const int* __restrict__ off,
                                                    const int2* __restrict__ edges, int N) {
    int g = (blockIdx.x * 256 + threadIdx.x) >> 3;   // row
    int l = threadIdx.x & 7;                          // lane-in-group
    if (g >= N) return;
    int s = off[g], e = off[g + 1];
    float a0 = 0.f, a1 = 0.f, a2 = 0.f, a3 = 0.f,
          a4 = 0.f, a5 = 0.f, a6 = 0.f, a7 = 0.f;
#define ACC8(r, v)                                                    \
    do {                                                              \
        a0 += (v) * __uint_as_float((r).x << 16);                     \
        a1 += (v) * __uint_as_float((r).x & 0xffff0000u);             \
        a2 += (v) * __uint_as_float((r).y << 16);                     \
        a3 += (v) * __uint_as_float((r).y & 0xffff0000u);             \
        a4 += (v) * __uint_as_float((r).z << 16);                     \
        a5 += (v) * __uint_as_float((r).z & 0xffff0000u);             \
        a6 += (v) * __uint_as_float((r).w << 16);                     \
        a7 += (v) * __uint_as_float((r).w & 0xffff0000u);             \
    } while (0)

    int i = s;
    for (; i + 4 <= e; i += 4) {
        int4 mA = *(const int4*)(edges + i);       // edges i, i+1
        int4 mB = *(const int4*)(edges + i + 2);   // edges i+2, i+3
        uint4 r0 = *(const uint4*)(xh + (size_t)mA.x * 32 + l * 4);
        uint4 r1 = *(const uint4*)(xh + (size_t)mA.z * 32 + l * 4);
        uint4 r2 = *(const uint4*)(xh + (size_t)mB.x * 32 + l * 4);
        uint4 r3 = *(const uint4*)(xh + (size_t)mB.z * 32 + l * 4);
        float v0 = __int_as_float(mA.y), v1 = __int_as_float(mA.w);
        float v2 = __int_as_float(mB.y), v3 = __int_as_float(mB.w);
        ACC8(r0, v0);
        ACC8(r1, v1);
        ACC8(r2, v2);
        ACC8(r3, v3);
    }
    for (; i < e; ++i) {
        int2 m = edges[i];
        uint4 rv = *(const uint4*)(xh + (size_t)m.x * 32 + l * 4);
        float v = __int_as_float(m.y);
        ACC8(rv, v);
    }
#undef ACC8
    uint4 out;
    out.x = pk_bf16(a0, a1);
    out.y = pk_bf16(a2, a3);
    out.z = pk_bf16(a4, a5);
    out.w = pk_bf16(a6, a7);
    *(uint4*)(yh + (size_t)g * 32 + l * 4) = out;
}

// ---------------- drug-row accumulation ----------------

__global__ __launch_bounds__(256) void gather_init_kernel(float* __restrict__ sacc,
                                                          const float* __restrict__ src,
                                                          const int* __restrict__ drugs, int B) {
    int idx = blockIdx.x * 256 + threadIdx.x;
    if (idx >= B * 64) return;
    int i = idx >> 6, d = idx & 63;
    sacc[idx] = src[(size_t)drugs[i] * 64 + d];
}

// add bf16 row (32 packed dwords) into f32 sacc
__global__ __launch_bounds__(256) void gather_addh_kernel(float* __restrict__ sacc,
                                                          const u32* __restrict__ srch,
                                                          const int* __restrict__ drugs, int B) {
    int idx = blockIdx.x * 256 + threadIdx.x;
    if (idx >= B * 32) return;
    int i = idx >> 5, k = idx & 31;
    u32 u = srch[(size_t)drugs[i] * 32 + k];
    sacc[i * 64 + 2 * k]     += __uint_as_float(u << 16);
    sacc[i * 64 + 2 * k + 1] += __uint_as_float(u & 0xffff0000u);
}

// gamma[i] = || sacc[i] * 0.2 ||^2  (wave per drug row)
__global__ __launch_bounds__(256) void gamma_kernel(const float* __restrict__ sacc,
                                                    float* __restrict__ out, int B) {
    int w = (blockIdx.x * 256 + threadIdx.x) >> 6;
    int lane = threadIdx.x & 63;
    if (w >= B) return;
    float v = sacc[(size_t)w * 64 + lane] * 0.2f;
    v = v * v;
    for (int o = 32; o > 0; o >>= 1) v += __shfl_down(v, o, 64);
    if (lane == 0) out[w] = v;
}

extern "C" void kernel_launch(void* const* d_in, const int* in_sizes, int n_in,
                              void* d_out, int out_size, void* d_ws, size_t ws_size,
                              hipStream_t stream) {
    (void)n_in; (void)ws_size; (void)out_size;
    const float* emb       = (const float*)d_in[0];
    const float* edge_vals = (const float*)d_in[1];
    const int*   edge_row  = (const int*)d_in[2];
    const int*   edge_col  = (const int*)d_in[3];
    const int*   drugs     = (const int*)d_in[4];
    int N = in_sizes[0] / 64;
    int E = in_sizes[1];
    int B = in_sizes[4];
    float* gamma_out = (float*)d_out;

    int nb = (N + RB - 1) >> RB_SHIFT;          // 1563
    int nchunks = (E + CHUNK - 1) / CHUNK;      // 391
    int M = nb * nchunks;

    char* ws = (char*)d_ws;
    size_t o = 0;
    auto alloc = [&](size_t bytes) -> void* {
        o = (o + 255) & ~(size_t)255;
        void* p = ws + o;
        o += bytes;
        return p;
    };
    size_t ebytes = (size_t)E * 8;
    size_t hbytes = (size_t)N * 32 * 4;          // bf16 state buffer (N x 32 dwords)
    int*   cmat    = (int*)alloc((size_t)M * 4);
    int*   partial = (int*)alloc(1024);
    int*   boff    = (int*)alloc((size_t)(nb + 1) * 4);
    int*   off     = (int*)alloc((size_t)(N + 1) * 4);
    char*  reg0    = (char*)alloc(ebytes > hbytes ? ebytes : hbytes);
    int2*  ein     = (int2*)reg0;               // dead after bsort
    u32*   embh    = (u32*)reg0;                // aliases ein
    int2*  eout    = (int2*)alloc(ebytes);
    u32*   bufHA   = (u32*)alloc(hbytes);
    u32*   bufHB   = (u32*)alloc(hbytes);
    float* sacc    = (float*)alloc((size_t)B * 64 * 4);

    // ---- atomic-free CSR build ----
    countA_kernel<<<nchunks, 256, 0, stream>>>(edge_row, cmat, E, nb, nchunks);
    int nscan = (M + SCAN_CHUNK - 1) / SCAN_CHUNK;
    scanA_kernel<<<nscan, 256, 0, stream>>>(cmat, partial, M);
    scanB_kernel<<<1, 256, 0, stream>>>(partial, nscan);
    scanC_kernel<<<nscan, 256, 0, stream>>>(cmat, partial, M);
    extract_boff_kernel<<<(nb + 256) / 256, 256, 0, stream>>>(cmat, boff, nb, nchunks, E);
    part2_kernel<<<nchunks, 256, 0, stream>>>(edge_row, edge_col, edge_vals,
                                              cmat, ein, E, nb, nchunks);
    bsort_kernel<<<nb, 256, 0, stream>>>(boff, ein, eout, off, N);

    // ---- bf16 conversion of e0 (after bsort: embh aliases ein) ----
    int n32 = N * 32;
    cvt_kernel<<<(n32 + 255) / 256, 256, 0, stream>>>(emb, embh, n32);

    // ---- 5-term sum over drug rows ----
    int gatherGrid64 = (B * 64 + 255) / 256;
    int gatherGrid32 = (B * 32 + 255) / 256;
    gather_init_kernel<<<gatherGrid64, 256, 0, stream>>>(sacc, emb, drugs, B);

    int spmmGrid = (N * 8 + 255) / 256;
    spmmh_kernel<<<spmmGrid, 256, 0, stream>>>(embh, bufHA, off, eout, N);   // G e0
    gather_addh_kernel<<<gatherGrid32, 256, 0, stream>>>(sacc, bufHA, drugs, B);
    spmmh_kernel<<<spmmGrid, 256, 0, stream>>>(bufHA, bufHB, off, eout, N);  // G^2 e0
    gather_addh_kernel<<<gatherGrid32, 256, 0, stream>>>(sacc, bufHB, drugs, B);
    spmmh_kernel<<<spmmGrid, 256, 0, stream>>>(bufHB, bufHA, off, eout, N);  // G^3 e0
    gather_addh_kernel<<<gatherGrid32, 256, 0, stream>>>(sacc, bufHA, drugs, B);
    spmmh_kernel<<<spmmGrid, 256, 0, stream>>>(bufHA, bufHB, off, eout, N);  // G^4 e0
    gather_addh_kernel<<<gatherGrid32, 256, 0, stream>>>(sacc, bufHB, drugs, B);

    gamma_kernel<<<(B + 3) / 4, 256, 0, stream>>>(sacc, gamma_out, B);
}

// Round 7
// 332.759 us; speedup vs baseline: 15.8263x; 1.0525x over previous
//
#include <hip/hip_runtime.h>

// gamma[i] = || (e0 + G e0 + G^2 e0 + G^3 e0 + G^4 e0)/5 [drugs[i]] ||^2
// R7: part2 write-amp fix — CHUNK 8192->16384 (runs 5.2->10.5 edges, amp
// 3.4x->~1.7x), 512 threads, int4-vectorized chunk reads in countA/part2.
// bf16 d-chain + eighth-wave spmmh unchanged from R6.

typedef unsigned int u32;

#define RB 64
#define RB_SHIFT 6
#define NBMAX 2048          // max buckets (N <= 131072)
#define CHUNK 16384         // edges per partition chunk
#define SCAN_CHUNK 4096

// ---------------- CSR build ----------------

__global__ __launch_bounds__(512) void countA_kernel(const int* __restrict__ row,
                                                     int* __restrict__ cmat,
                                                     int E, int nb, int nchunks) {
    __shared__ int lcnt[NBMAX];
    int t = threadIdx.x, c = blockIdx.x;
    int s = c * CHUNK, e = min(s + CHUNK, E);
    for (int i = t; i < nb; i += 512) lcnt[i] = 0;
    __syncthreads();
    for (int i = s + t * 4; i < e; i += 512 * 4) {
        if (i + 3 < e) {
            int4 r4 = *(const int4*)(row + i);
            atomicAdd(&lcnt[r4.x >> RB_SHIFT], 1);
            atomicAdd(&lcnt[r4.y >> RB_SHIFT], 1);
            atomicAdd(&lcnt[r4.z >> RB_SHIFT], 1);
            atomicAdd(&lcnt[r4.w >> RB_SHIFT], 1);
        } else {
            for (int k = i; k < e; ++k) atomicAdd(&lcnt[row[k] >> RB_SHIFT], 1);
        }
    }
    __syncthreads();
    for (int b = t; b < nb; b += 512)
        cmat[(size_t)b * nchunks + c] = lcnt[b];
}

__global__ __launch_bounds__(256) void scanA_kernel(const int* __restrict__ data,
                                                    int* __restrict__ partial, int M) {
    __shared__ int sdata[256];
    int t = threadIdx.x;
    int base = blockIdx.x * SCAN_CHUNK;
    int sum = 0;
#pragma unroll
    for (int j = 0; j < 16; ++j) {
        int idx = base + j * 256 + t;
        if (idx < M) sum += data[idx];
    }
    sdata[t] = sum;
    __syncthreads();
    for (int d = 128; d > 0; d >>= 1) {
        if (t < d) sdata[t] += sdata[t + d];
        __syncthreads();
    }
    if (t == 0) partial[blockIdx.x] = sdata[0];
}

__global__ __launch_bounds__(256) void scanB_kernel(int* __restrict__ partial, int nblk) {
    __shared__ int sdata[256];
    int t = threadIdx.x;
    int v = (t < nblk) ? partial[t] : 0;
    sdata[t] = v;
    __syncthreads();
    for (int d = 1; d < 256; d <<= 1) {
        int tmp = (t >= d) ? sdata[t - d] : 0;
        __syncthreads();
        sdata[t] += tmp;
        __syncthreads();
    }
    if (t < nblk) partial[t] = sdata[t] - v;
}

__global__ __launch_bounds__(256) void scanC_kernel(int* __restrict__ data,
                                                    const int* __restrict__ partial, int M) {
    __shared__ int sdata[256];
    int t = threadIdx.x;
    int base = blockIdx.x * SCAN_CHUNK;
    int v[16];
    int sum = 0;
#pragma unroll
    for (int j = 0; j < 16; ++j) {
        int idx = base + t * 16 + j;
        v[j] = (idx < M) ? data[idx] : 0;
        sum += v[j];
    }
    sdata[t] = sum;
    __syncthreads();
    for (int d = 1; d < 256; d <<= 1) {
        int tmp = (t >= d) ? sdata[t - d] : 0;
        __syncthreads();
        sdata[t] += tmp;
        __syncthreads();
    }
    int excl = sdata[t] - sum + partial[blockIdx.x];
#pragma unroll
    for (int j = 0; j < 16; ++j) {
        int idx = base + t * 16 + j;
        if (idx < M) data[idx] = excl;
        excl += v[j];
    }
}

__global__ __launch_bounds__(256) void extract_boff_kernel(const int* __restrict__ cmat,
                                                           int* __restrict__ boff,
                                                           int nb, int nchunks, int E) {
    int b = blockIdx.x * 256 + threadIdx.x;
    if (b < nb) boff[b] = cmat[(size_t)b * nchunks];
    if (b == nb) boff[nb] = E;
}

__global__ __launch_bounds__(512) void part2_kernel(const int* __restrict__ row,
                                                    const int* __restrict__ col,
                                                    const float* __restrict__ val,
                                                    const int* __restrict__ cmat,
                                                    int2* __restrict__ edges,
                                                    int E, int nb, int nchunks) {
    __shared__ int lcur[NBMAX];
    int t = threadIdx.x, c = blockIdx.x;
    int s = c * CHUNK, e = min(s + CHUNK, E);
    for (int b = t; b < nb; b += 512)
        lcur[b] = cmat[(size_t)b * nchunks + c];
    __syncthreads();
    for (int i = s + t * 4; i < e; i += 512 * 4) {
        if (i + 3 < e) {
            int4   r4 = *(const int4*)(row + i);
            int4   c4 = *(const int4*)(col + i);
            float4 v4 = *(const float4*)(val + i);
            int lo0 = atomicAdd(&lcur[r4.x >> RB_SHIFT], 1);
            int lo1 = atomicAdd(&lcur[r4.y >> RB_SHIFT], 1);
            int lo2 = atomicAdd(&lcur[r4.z >> RB_SHIFT], 1);
            int lo3 = atomicAdd(&lcur[r4.w >> RB_SHIFT], 1);
            edges[lo0] = make_int2(((r4.x & (RB - 1)) << 20) | c4.x, __float_as_int(v4.x));
            edges[lo1] = make_int2(((r4.y & (RB - 1)) << 20) | c4.y, __float_as_int(v4.y));
            edges[lo2] = make_int2(((r4.z & (RB - 1)) << 20) | c4.z, __float_as_int(v4.z));
            edges[lo3] = make_int2(((r4.w & (RB - 1)) << 20) | c4.w, __float_as_int(v4.w));
        } else {
            for (int k = i; k < e; ++k) {
                int r = row[k];
                int lo = atomicAdd(&lcur[r >> RB_SHIFT], 1);
                edges[lo] = make_int2(((r & (RB - 1)) << 20) | col[k],
                                      __float_as_int(val[k]));
            }
        }
    }
}

__global__ __launch_bounds__(256) void bsort_kernel(const int* __restrict__ boff,
                                                    const int2* __restrict__ ein,
                                                    int2* __restrict__ eout,
                                                    int* __restrict__ off, int N) {
    __shared__ int rcnt[RB];
    __shared__ int rcur[RB];
    int b = blockIdx.x, t = threadIdx.x;
    int s = boff[b], e = boff[b + 1];
    if (t < RB) rcnt[t] = 0;
    __syncthreads();
    for (int i = s + t; i < e; i += 256)
        atomicAdd(&rcnt[ein[i].x >> 20], 1);
    __syncthreads();
    if (t < RB) {
        int v = rcnt[t];
        int x = v;
        for (int d = 1; d < RB; d <<= 1) {
            int y = __shfl_up(x, d, 64);
            if (t >= d) x += y;
        }
        int excl = x - v;
        rcur[t] = excl;
        int idx = (b << RB_SHIFT) + t;
        if (idx <= N) off[idx] = s + excl;
        if (t == RB - 1) {
            int idx2 = (b << RB_SHIFT) + RB;
            if (idx2 <= N) off[idx2] = e;
        }
    }
    __syncthreads();
    for (int i = s + t; i < e; i += 256) {
        int2 m = ein[i];
        int pos = atomicAdd(&rcur[m.x >> 20], 1);
        eout[s + pos] = make_int2(m.x & 0xFFFFF, m.y);
    }
}

// ---------------- bf16 helpers ----------------

static __device__ inline u32 pk_bf16(float lo, float hi) {
    u32 a = __float_as_uint(lo), b = __float_as_uint(hi);
    a += 0x7fffu + ((a >> 16) & 1u);   // RNE
    b += 0x7fffu + ((b >> 16) & 1u);
    return (a >> 16) | (b & 0xffff0000u);
}

__global__ __launch_bounds__(256) void cvt_kernel(const float* __restrict__ src,
                                                  u32* __restrict__ dst, int n32) {
    int idx = blockIdx.x * 256 + threadIdx.x;
    if (idx >= n32) return;
    float2 f = *(const float2*)(src + (size_t)idx * 2);
    dst[idx] = pk_bf16(f.x, f.y);
}

// ---------------- SpMM: bf16 in, bf16 out ----------------
__global__ __launch_bounds__(256) void spmmh_kernel(const u32* __restrict__ xh,
                                                    u32* __restrict__ yh,
                                                    const int* __restrict__ off,
                                                    const int2* __restrict__ edges, int N) {
    int g = (blockIdx.x * 256 + threadIdx.x) >> 3;   // row
    int l = threadIdx.x & 7;                          // lane-in-group
    if (g >= N) return;
    int s = off[g], e = off[g + 1];
    float a0 = 0.f, a1 = 0.f, a2 = 0.f, a3 = 0.f,
          a4 = 0.f, a5 = 0.f, a6 = 0.f, a7 = 0.f;
#define ACC8(r, v)                                                    \
    do {                                                              \
        a0 += (v) * __uint_as_float((r).x << 16);                     \
        a1 += (v) * __uint_as_float((r).x & 0xffff0000u);             \
        a2 += (v) * __uint_as_float((r).y << 16);                     \
        a3 += (v) * __uint_as_float((r).y & 0xffff0000u);             \
        a4 += (v) * __uint_as_float((r).z << 16);                     \
        a5 += (v) * __uint_as_float((r).z & 0xffff0000u);             \
        a6 += (v) * __uint_as_float((r).w << 16);                     \
        a7 += (v) * __uint_as_float((r).w & 0xffff0000u);             \
    } while (0)

    int i = s;
    for (; i + 4 <= e; i += 4) {
        int4 mA = *(const int4*)(edges + i);
        int4 mB = *(const int4*)(edges + i + 2);
        uint4 r0 = *(const uint4*)(xh + (size_t)mA.x * 32 + l * 4);
        uint4 r1 = *(const uint4*)(xh + (size_t)mA.z * 32 + l * 4);
        uint4 r2 = *(const uint4*)(xh + (size_t)mB.x * 32 + l * 4);
        uint4 r3 = *(const uint4*)(xh + (size_t)mB.z * 32 + l * 4);
        float v0 = __int_as_float(mA.y), v1 = __int_as_float(mA.w);
        float v2 = __int_as_float(mB.y), v3 = __int_as_float(mB.w);
        ACC8(r0, v0);
        ACC8(r1, v1);
        ACC8(r2, v2);
        ACC8(r3, v3);
    }
    for (; i < e; ++i) {
        int2 m = edges[i];
        uint4 rv = *(const uint4*)(xh + (size_t)m.x * 32 + l * 4);
        float v = __int_as_float(m.y);
        ACC8(rv, v);
    }
#undef ACC8
    uint4 out;
    out.x = pk_bf16(a0, a1);
    out.y = pk_bf16(a2, a3);
    out.z = pk_bf16(a4, a5);
    out.w = pk_bf16(a6, a7);
    *(uint4*)(yh + (size_t)g * 32 + l * 4) = out;
}

// ---------------- drug-row accumulation ----------------

__global__ __launch_bounds__(256) void gather_init_kernel(float* __restrict__ sacc,
                                                          const float* __restrict__ src,
                                                          const int* __restrict__ drugs, int B) {
    int idx = blockIdx.x * 256 + threadIdx.x;
    if (idx >= B * 64) return;
    int i = idx >> 6, d = idx & 63;
    sacc[idx] = src[(size_t)drugs[i] * 64 + d];
}

__global__ __launch_bounds__(256) void gather_addh_kernel(float* __restrict__ sacc,
                                                          const u32* __restrict__ srch,
                                                          const int* __restrict__ drugs, int B) {
    int idx = blockIdx.x * 256 + threadIdx.x;
    if (idx >= B * 32) return;
    int i = idx >> 5, k = idx & 31;
    u32 u = srch[(size_t)drugs[i] * 32 + k];
    sacc[i * 64 + 2 * k]     += __uint_as_float(u << 16);
    sacc[i * 64 + 2 * k + 1] += __uint_as_float(u & 0xffff0000u);
}

__global__ __launch_bounds__(256) void gamma_kernel(const float* __restrict__ sacc,
                                                    float* __restrict__ out, int B) {
    int w = (blockIdx.x * 256 + threadIdx.x) >> 6;
    int lane = threadIdx.x & 63;
    if (w >= B) return;
    float v = sacc[(size_t)w * 64 + lane] * 0.2f;
    v = v * v;
    for (int o = 32; o > 0; o >>= 1) v += __shfl_down(v, o, 64);
    if (lane == 0) out[w] = v;
}

extern "C" void kernel_launch(void* const* d_in, const int* in_sizes, int n_in,
                              void* d_out, int out_size, void* d_ws, size_t ws_size,
                              hipStream_t stream) {
    (void)n_in; (void)ws_size; (void)out_size;
    const float* emb       = (const float*)d_in[0];
    const float* edge_vals = (const float*)d_in[1];
    const int*   edge_row  = (const int*)d_in[2];
    const int*   edge_col  = (const int*)d_in[3];
    const int*   drugs     = (const int*)d_in[4];
    int N = in_sizes[0] / 64;
    int E = in_sizes[1];
    int B = in_sizes[4];
    float* gamma_out = (float*)d_out;

    int nb = (N + RB - 1) >> RB_SHIFT;          // 1563
    int nchunks = (E + CHUNK - 1) / CHUNK;      // 196
    int M = nb * nchunks;

    char* ws = (char*)d_ws;
    size_t o = 0;
    auto alloc = [&](size_t bytes) -> void* {
        o = (o + 255) & ~(size_t)255;
        void* p = ws + o;
        o += bytes;
        return p;
    };
    size_t ebytes = (size_t)E * 8;
    size_t hbytes = (size_t)N * 32 * 4;
    int*   cmat    = (int*)alloc((size_t)M * 4);
    int*   partial = (int*)alloc(1024);
    int*   boff    = (int*)alloc((size_t)(nb + 1) * 4);
    int*   off     = (int*)alloc((size_t)(N + 1) * 4);
    char*  reg0    = (char*)alloc(ebytes > hbytes ? ebytes : hbytes);
    int2*  ein     = (int2*)reg0;               // dead after bsort
    u32*   embh    = (u32*)reg0;                // aliases ein
    int2*  eout    = (int2*)alloc(ebytes);
    u32*   bufHA   = (u32*)alloc(hbytes);
    u32*   bufHB   = (u32*)alloc(hbytes);
    float* sacc    = (float*)alloc((size_t)B * 64 * 4);

    // ---- atomic-free CSR build ----
    countA_kernel<<<nchunks, 512, 0, stream>>>(edge_row, cmat, E, nb, nchunks);
    int nscan = (M + SCAN_CHUNK - 1) / SCAN_CHUNK;
    scanA_kernel<<<nscan, 256, 0, stream>>>(cmat, partial, M);
    scanB_kernel<<<1, 256, 0, stream>>>(partial, nscan);
    scanC_kernel<<<nscan, 256, 0, stream>>>(cmat, partial, M);
    extract_boff_kernel<<<(nb + 256) / 256, 256, 0, stream>>>(cmat, boff, nb, nchunks, E);
    part2_kernel<<<nchunks, 512, 0, stream>>>(edge_row, edge_col, edge_vals,
                                              cmat, ein, E, nb, nchunks);
    bsort_kernel<<<nb, 256, 0, stream>>>(boff, ein, eout, off, N);

    // ---- bf16 conversion of e0 (embh aliases ein, dead after bsort) ----
    int n32 = N * 32;
    cvt_kernel<<<(n32 + 255) / 256, 256, 0, stream>>>(emb, embh, n32);

    // ---- 5-term sum over drug rows ----
    int gatherGrid64 = (B * 64 + 255) / 256;
    int gatherGrid32 = (B * 32 + 255) / 256;
    gather_init_kernel<<<gatherGrid64, 256, 0, stream>>>(sacc, emb, drugs, B);

    int spmmGrid = (N * 8 + 255) / 256;
    spmmh_kernel<<<spmmGrid, 256, 0, stream>>>(embh, bufHA, off, eout, N);   // G e0
    gather_addh_kernel<<<gatherGrid32, 256, 0, stream>>>(sacc, bufHA, drugs, B);
    spmmh_kernel<<<spmmGrid, 256, 0, stream>>>(bufHA, bufHB, off, eout, N);  // G^2 e0
    gather_addh_kernel<<<gatherGrid32, 256, 0, stream>>>(sacc, bufHB, drugs, B);
    spmmh_kernel<<<spmmGrid, 256, 0, stream>>>(bufHB, bufHA, off, eout, N);  // G^3 e0
    gather_addh_kernel<<<gatherGrid32, 256, 0, stream>>>(sacc, bufHA, drugs, B);
    spmmh_kernel<<<spmmGrid, 256, 0, stream>>>(bufHA, bufHB, off, eout, N);  // G^4 e0
    gather_addh_kernel<<<gatherGrid32, 256, 0, stream>>>(sacc, bufHB, drugs, B);

    gamma_kernel<<<(B + 3) / 4, 256, 0, stream>>>(sacc, gamma_out, B);
}